// Round 1
// baseline (1096.627 us; speedup 1.0000x reference)
//
#include <hip/hip_runtime.h>
#include <math.h>

typedef unsigned short u16;
typedef __bf16 bf16x8 __attribute__((ext_vector_type(8)));
typedef float f32x4 __attribute__((ext_vector_type(4)));
typedef short s16x8 __attribute__((ext_vector_type(8)));

#define DM 2048
#define NB 4
#define SEQ 2048
#define PAST_N 2048
#define CS 4096

__device__ __forceinline__ u16 f2bf(float f) {
  unsigned u = __float_as_uint(f);
  u += 0x7fff + ((u >> 16) & 1);
  return (u16)(u >> 16);
}
__device__ __forceinline__ float bf2f(u16 h) {
  return __uint_as_float(((unsigned)h) << 16);
}

__device__ __forceinline__ void gl_lds16(const u16* g, u16* l) {
  __builtin_amdgcn_global_load_lds(
      (const __attribute__((address_space(1))) unsigned*)g,
      (__attribute__((address_space(3))) unsigned*)l, 16, 0, 0);
}

// C[M,N] = A[M,K] * B[N,K]^T  (both operands K-contiguous), bf16 in, fp32 accum.
// EPI==0: fp32 out (+bias, *scale). EPI==1: bf16 out (+bias, *scale).
// REMAP: output row m -> (m>>11)*CS + PAST_N + (m&2047)  (KV-cache placement)
template <int EPI, bool REMAP>
__global__ __launch_bounds__(256) void gemm_bt(
    const u16* __restrict__ A, const u16* __restrict__ B,
    float* __restrict__ Cf, u16* __restrict__ Cb, const float* __restrict__ bias,
    int K, int lda, int ldb, int ldc, long strA, long strB, long strC,
    float scale) {
  __shared__ u16 shA[128 * 32];
  __shared__ u16 shB[128 * 32];
  const int t = threadIdx.x;
  const int lane = t & 63;
  const int w = t >> 6;
  const int wr = w >> 1, wc = w & 1;
  const long bz = blockIdx.z;
  const int brow = blockIdx.y * 128;
  const int bcol = blockIdx.x * 128;
  const u16* Ab = A + bz * strA;
  const u16* Bb = B + bz * strB;

  const u16* gA0 = Ab + (long)(brow + (t >> 2)) * lda + (t & 3) * 8;
  const u16* gA1 = Ab + (long)(brow + 64 + (t >> 2)) * lda + (t & 3) * 8;
  const u16* gB0 = Bb + (long)(bcol + (t >> 2)) * ldb + (t & 3) * 8;
  const u16* gB1 = Bb + (long)(bcol + 64 + (t >> 2)) * ldb + (t & 3) * 8;
  u16* lA0 = &shA[(w * 64) * 8];
  u16* lA1 = &shA[(256 + w * 64) * 8];
  u16* lB0 = &shB[(w * 64) * 8];
  u16* lB1 = &shB[(256 + w * 64) * 8];

  f32x4 acc[4][4] = {};

  for (int k0 = 0; k0 < K; k0 += 32) {
    gl_lds16(gA0, lA0);
    gl_lds16(gA1, lA1);
    gl_lds16(gB0, lB0);
    gl_lds16(gB1, lB1);
    gA0 += 32; gA1 += 32; gB0 += 32; gB1 += 32;
    __syncthreads();
    bf16x8 af[4], bfr[4];
#pragma unroll
    for (int m = 0; m < 4; ++m)
      af[m] = *(const bf16x8*)&shA[(wr * 64 + m * 16 + (lane & 15)) * 32 + (lane >> 4) * 8];
#pragma unroll
    for (int n = 0; n < 4; ++n)
      bfr[n] = *(const bf16x8*)&shB[(wc * 64 + n * 16 + (lane & 15)) * 32 + (lane >> 4) * 8];
#pragma unroll
    for (int m = 0; m < 4; ++m)
#pragma unroll
      for (int n = 0; n < 4; ++n)
        acc[m][n] = __builtin_amdgcn_mfma_f32_16x16x32_bf16(af[m], bfr[n], acc[m][n], 0, 0, 0);
    __syncthreads();
  }

  const long cb = bz * strC;
#pragma unroll
  for (int m = 0; m < 4; ++m) {
    const int r0 = wr * 64 + m * 16 + (lane >> 4) * 4;
#pragma unroll
    for (int n = 0; n < 4; ++n) {
      const int c = bcol + wc * 64 + n * 16 + (lane & 15);
      const float bv = bias ? bias[c] : 0.0f;
#pragma unroll
      for (int r = 0; r < 4; ++r) {
        const int row = brow + r0 + r;
        const long orow = REMAP ? (long)((row >> 11) * CS + PAST_N + (row & (SEQ - 1)))
                                : (long)row;
        const float val = (acc[m][n][r] + bv) * scale;
        if (EPI == 0)
          Cf[cb + orow * (long)ldc + c] = val;
        else
          Cb[cb + orow * (long)ldc + c] = f2bf(val);
      }
    }
  }
}

// fp32 -> bf16 cast, 4 elems/thread, grid exactly covers n/4
__global__ __launch_bounds__(256) void cast_bf16_kn(const float* __restrict__ in,
                                                    u16* __restrict__ out) {
  const int i = blockIdx.x * 256 + threadIdx.x;
  const float4 v = ((const float4*)in)[i];
  ushort4 o;
  o.x = f2bf(v.x); o.y = f2bf(v.y); o.z = f2bf(v.z); o.w = f2bf(v.w);
  ((ushort4*)out)[i] = o;
}

// past_k/past_v -> cache rows [b, 0..PAST), fp32 copy. blockIdx.z: 0=k,1=v
__global__ __launch_bounds__(256) void copy_past_kv(const float* __restrict__ pk,
                                                    const float* __restrict__ pv,
                                                    float* __restrict__ kc,
                                                    float* __restrict__ vc) {
  const int i = blockIdx.x * 256 + threadIdx.x;  // < NB*PAST_N*DM/4
  const float* src = blockIdx.z ? pv : pk;
  float* dst = blockIdx.z ? vc : kc;
  const int d4 = DM / 4;
  const int row = i / d4;
  const int col = i - row * d4;
  const int b = row >> 11, p = row & (PAST_N - 1);
  ((float4*)dst)[((long)(b * CS + p)) * d4 + col] = ((const float4*)src)[i];
}

// v_cache [b][k][d] fp32 -> vT [b][d][k] bf16
__global__ __launch_bounds__(256) void transpose_cast(const float* __restrict__ vcache,
                                                      u16* __restrict__ vt) {
  __shared__ float tile[32][33];
  const int b = blockIdx.z;
  const int k0 = blockIdx.x * 32, d0 = blockIdx.y * 32;
  const int tx = threadIdx.x & 31, ty = threadIdx.x >> 5;
  const float* src = vcache + (long)b * CS * DM;
#pragma unroll
  for (int j = 0; j < 4; ++j)
    tile[ty + 8 * j][tx] = src[(long)(k0 + ty + 8 * j) * DM + d0 + tx];
  __syncthreads();
  u16* dst = vt + (long)b * DM * CS;
#pragma unroll
  for (int j = 0; j < 4; ++j)
    dst[(long)(d0 + ty + 8 * j) * CS + k0 + tx] = f2bf(tile[tx][ty + 8 * j]);
}

// in-place row softmax over bf16 scores, row length CS=4096, one block/row
__global__ __launch_bounds__(256) void softmax_rows(u16* __restrict__ s) {
  const long row = blockIdx.x;
  u16* p = s + row * CS;
  const int t = threadIdx.x;
  const int lane = t & 63, w = t >> 6;
  float v[16];
  s16x8 c0 = ((const s16x8*)p)[t * 2];
  s16x8 c1 = ((const s16x8*)p)[t * 2 + 1];
#pragma unroll
  for (int i = 0; i < 8; ++i) {
    v[i] = bf2f((u16)c0[i]);
    v[8 + i] = bf2f((u16)c1[i]);
  }
  float m = v[0];
#pragma unroll
  for (int i = 1; i < 16; ++i) m = fmaxf(m, v[i]);
#pragma unroll
  for (int o = 32; o >= 1; o >>= 1) m = fmaxf(m, __shfl_xor(m, o, 64));
  __shared__ float red[4];
  if (lane == 0) red[w] = m;
  __syncthreads();
  m = fmaxf(fmaxf(red[0], red[1]), fmaxf(red[2], red[3]));
  float sum = 0.f;
#pragma unroll
  for (int i = 0; i < 16; ++i) {
    v[i] = __expf(v[i] - m);
    sum += v[i];
  }
#pragma unroll
  for (int o = 32; o >= 1; o >>= 1) sum += __shfl_xor(sum, o, 64);
  __syncthreads();
  if (lane == 0) red[w] = sum;
  __syncthreads();
  sum = red[0] + red[1] + red[2] + red[3];
  const float inv = 1.0f / sum;
#pragma unroll
  for (int i = 0; i < 8; ++i) {
    c0[i] = (short)f2bf(v[i] * inv);
    c1[i] = (short)f2bf(v[8 + i] * inv);
  }
  ((s16x8*)p)[t * 2] = c0;
  ((s16x8*)p)[t * 2 + 1] = c1;
}

extern "C" void kernel_launch(void* const* d_in, const int* in_sizes, int n_in,
                              void* d_out, int out_size, void* d_ws, size_t ws_size,
                              hipStream_t stream) {
  const float* x  = (const float*)d_in[0];
  const float* pk = (const float*)d_in[1];
  const float* pv = (const float*)d_in[2];
  const float* Wq = (const float*)d_in[3];
  const float* bq = (const float*)d_in[4];
  const float* Wk = (const float*)d_in[5];
  const float* bk = (const float*)d_in[6];
  const float* Wv = (const float*)d_in[7];
  const float* bv = (const float*)d_in[8];
  const float* Wo = (const float*)d_in[9];
  const float* bo = (const float*)d_in[10];

  float* out = (float*)d_out;
  float* kc = out + (long)NB * SEQ * DM;   // k_cache [4][4096][2048] fp32
  float* vc = kc + (long)NB * CS * DM;     // v_cache

  u16* ws = (u16*)d_ws;
  u16* xb  = ws;              // x bf16 [8192][2048]; reused as attn bf16 later
  u16* wqb = ws + 16777216;
  u16* wkb = wqb + 4194304;
  u16* wvb = wkb + 4194304;
  u16* wob = wvb + 4194304;
  u16* qb  = ws + 33554432;   // q bf16 (scaled) [8192][2048]
  u16* kb  = ws + 50331648;   // k_cache bf16 [4][4096][2048]
  u16* vtb = ws + 83886080;   // v_cache^T bf16 [4][2048][4096]
  u16* sc  = ws + 117440512;  // scores/weights bf16 [4][2048][4096]

  const float qscale = 0.022097086912079608f;  // 1/sqrt(2048)

  cast_bf16_kn<<<16384, 256, 0, stream>>>(x, xb);
  cast_bf16_kn<<<4096, 256, 0, stream>>>(Wq, wqb);
  cast_bf16_kn<<<4096, 256, 0, stream>>>(Wk, wkb);
  cast_bf16_kn<<<4096, 256, 0, stream>>>(Wv, wvb);
  cast_bf16_kn<<<4096, 256, 0, stream>>>(Wo, wob);

  // Q = (x Wq^T + bq) * qscale -> bf16
  gemm_bt<1, false><<<dim3(16, 64, 1), 256, 0, stream>>>(
      xb, wqb, nullptr, qb, bq, 2048, 2048, 2048, 2048, 0, 0, 0, qscale);
  // K,V -> fp32 straight into d_out cache (rows PAST..)
  gemm_bt<0, true><<<dim3(16, 64, 1), 256, 0, stream>>>(
      xb, wkb, kc, nullptr, bk, 2048, 2048, 2048, 2048, 0, 0, 0, 1.0f);
  gemm_bt<0, true><<<dim3(16, 64, 1), 256, 0, stream>>>(
      xb, wvb, vc, nullptr, bv, 2048, 2048, 2048, 2048, 0, 0, 0, 1.0f);

  copy_past_kv<<<dim3(16384, 1, 2), 256, 0, stream>>>(pk, pv, kc, vc);

  cast_bf16_kn<<<32768, 256, 0, stream>>>(kc, kb);
  transpose_cast<<<dim3(128, 64, 4), 256, 0, stream>>>(vc, vtb);

  // scores = q_scaled . k_cache^T -> bf16 [4][2048][4096]
  gemm_bt<1, false><<<dim3(32, 16, 4), 256, 0, stream>>>(
      qb, kb, nullptr, sc, nullptr, 2048, 2048, 2048, 4096,
      2048L * 2048, 4096L * 2048, 2048L * 4096, 1.0f);

  softmax_rows<<<8192, 256, 0, stream>>>(sc);

  // attn = weights . v_cache  (B = vT, K-contiguous) -> bf16 into xb
  gemm_bt<1, false><<<dim3(16, 16, 4), 256, 0, stream>>>(
      sc, vtb, nullptr, xb, nullptr, 4096, 4096, 4096, 2048,
      2048L * 4096, 2048L * 4096, 2048L * 2048, 1.0f);

  // out = attn Wo^T + bo -> fp32
  gemm_bt<0, false><<<dim3(16, 64, 1), 256, 0, stream>>>(
      xb, wob, out, nullptr, bo, 2048, 2048, 2048, 2048, 0, 0, 0, 1.0f);
}

// Round 2
// 780.143 us; speedup vs baseline: 1.4057x; 1.4057x over previous
//
#include <hip/hip_runtime.h>
#include <math.h>

typedef unsigned short u16;
typedef __bf16 bf16x8 __attribute__((ext_vector_type(8)));
typedef float f32x4 __attribute__((ext_vector_type(4)));
typedef short s16x8 __attribute__((ext_vector_type(8)));

#define DM 2048
#define NB 4
#define SEQ 2048
#define PAST_N 2048
#define CS 4096

__device__ __forceinline__ u16 f2bf(float f) {
  unsigned u = __float_as_uint(f);
  u += 0x7fff + ((u >> 16) & 1);
  return (u16)(u >> 16);
}
__device__ __forceinline__ float bf2f(u16 h) {
  return __uint_as_float(((unsigned)h) << 16);
}

__device__ __forceinline__ void gl_lds16(const u16* g, u16* l) {
  __builtin_amdgcn_global_load_lds(
      (const __attribute__((address_space(1))) unsigned*)g,
      (__attribute__((address_space(3))) unsigned*)l, 16, 0, 0);
}

// Swizzled LDS fragment read: tile is row-major [256 rows][64 k] bf16 (128B/row),
// stored with 16B-slot XOR swizzle: slot ^= (row&7). Read applies same XOR.
__device__ __forceinline__ bf16x8 ldsfrag(const u16* s, int row, int colb) {
  const int byte_off = (row * 128 + colb) ^ ((row & 7) << 4);
  return *(const bf16x8*)((const char*)s + byte_off);
}

// Stage one 256x64 bf16 tile (32KB) with 512 threads: 4 x global_load_lds(16B).
// LDS dest is linear (wave base + lane*16, HW requirement); the SOURCE column
// is pre-swizzled so that a swizzled read retrieves linear data (rule #21).
__device__ __forceinline__ void stage4(const u16* __restrict__ g, int ld,
                                       u16* lwb, int t) {
#pragma unroll
  for (int j = 0; j < 4; ++j) {
    const int c = j * 512 + t;          // 16B chunk index, 2048 total
    const int row = c >> 3;             // 8 chunks per 128B row
    const int slot = (c & 7) ^ (row & 7);
    gl_lds16(g + (long)row * ld + slot * 8, lwb + j * 4096);
  }
}

#define LOADA(mh)                                                       \
  _Pragma("unroll") for (int mi = 0; mi < 4; ++mi) {                    \
    const int rwa = wr * 128 + ((mh) * 4 + mi) * 16 + lr;               \
    a[mi][0] = ldsfrag(sA, rwa, kb0);                                   \
    a[mi][1] = ldsfrag(sA, rwa, 64 + kb0);                              \
  }

#define LOADB(nh)                                                       \
  _Pragma("unroll") for (int ni = 0; ni < 2; ++ni) {                    \
    const int rwb = wc * 64 + ((nh) * 2 + ni) * 16 + lr;                \
    b[ni][0] = ldsfrag(sB, rwb, kb0);                                   \
    b[ni][1] = ldsfrag(sB, rwb, 64 + kb0);                              \
  }

#define MM(mh, nh)                                                      \
  _Pragma("unroll") for (int kk = 0; kk < 2; ++kk)                      \
  _Pragma("unroll") for (int mi = 0; mi < 4; ++mi)                      \
  _Pragma("unroll") for (int ni = 0; ni < 2; ++ni)                      \
    acc[(mh) * 4 + mi][(nh) * 2 + ni] =                                 \
        __builtin_amdgcn_mfma_f32_16x16x32_bf16(                        \
            a[mi][kk], b[ni][kk], acc[(mh) * 4 + mi][(nh) * 2 + ni],    \
            0, 0, 0);

#define PHASE_SYNC                                                      \
  __builtin_amdgcn_s_barrier();                                         \
  asm volatile("s_waitcnt lgkmcnt(0)" ::: "memory");                    \
  __builtin_amdgcn_sched_barrier(0);

// C[M,N] = A[M,K] * B[N,K]^T, bf16 in, fp32 accum. 256x256 tile, BK=64,
// 8 waves (2Mx4N), each wave owns 128x64 output. Double-buffered swizzled LDS,
// 4-phase quadrant schedule, raw barriers + explicit waitcnt, setprio on MFMA.
// EPI: 0 = fp32 out, 1 = bf16 out, 2 = both. REMAP: KV-cache row placement.
template <int EPI, bool REMAP>
__global__ __launch_bounds__(512, 2) void gemm256(
    const u16* __restrict__ A, const u16* __restrict__ B,
    float* __restrict__ Cf, u16* __restrict__ Cb, const float* __restrict__ bias,
    int K, int lda, int ldb, int ldc, long strA, long strB, long strC,
    float scale) {
  __shared__ __align__(16) u16 shA[2][256 * 64];
  __shared__ __align__(16) u16 shB[2][256 * 64];
  const int t = threadIdx.x;
  const int lane = t & 63;
  const int w = t >> 6;
  const int wr = w >> 2, wc = w & 3;
  const int lr = lane & 15, kb0 = (lane >> 4) * 16;

  // T1: XCD-aware bijective swizzle of flattened block id (nwg % 8 == 0 here)
  const int gx = gridDim.x, gy = gridDim.y;
  const int nwg = gx * gy * gridDim.z;
  const int orig = blockIdx.x + gx * (blockIdx.y + gy * blockIdx.z);
  const int swz = (orig & 7) * (nwg >> 3) + (orig >> 3);
  const int bx = swz % gx;
  const int r1 = swz / gx;
  const int by = r1 % gy;
  const long bz = r1 / gy;
  const int brow = by * 256, bcol = bx * 256;

  const u16* Ab = A + bz * strA + (long)brow * lda;
  const u16* Bb = B + bz * strB + (long)bcol * ldb;

  // prologue: stage tile 0 into buf 0
  stage4(Ab, lda, &shA[0][w * 512], t);
  stage4(Bb, ldb, &shB[0][w * 512], t);
  asm volatile("s_waitcnt vmcnt(0)" ::: "memory");
  __builtin_amdgcn_s_barrier();

  f32x4 acc[8][4] = {};
  bf16x8 a[4][2], b[2][2];
  const u16* sA;
  const u16* sB;
  const int NT = K >> 6;

  for (int tt = 0; tt < NT; ++tt) {
    const int cur = tt & 1;
    sA = shA[cur];
    sB = shB[cur];
    const bool pf = (tt + 1 < NT);
    const int ko = (tt + 1) << 6;

    // ---- phase 0: quadrant (0,0); prefetch next A tile
    LOADA(0)
    LOADB(0)
    if (pf) stage4(Ab + ko, lda, &shA[cur ^ 1][w * 512], t);
    PHASE_SYNC
    __builtin_amdgcn_s_setprio(1);
    MM(0, 0)
    __builtin_amdgcn_s_setprio(0);
    __builtin_amdgcn_s_barrier();

    // ---- phase 1: quadrant (0,1); prefetch next B tile
    LOADB(1)
    if (pf) stage4(Bb + ko, ldb, &shB[cur ^ 1][w * 512], t);
    PHASE_SYNC
    __builtin_amdgcn_s_setprio(1);
    MM(0, 1)
    __builtin_amdgcn_s_setprio(0);
    __builtin_amdgcn_s_barrier();

    // ---- phase 2: quadrant (1,1)
    LOADA(1)
    PHASE_SYNC
    __builtin_amdgcn_s_setprio(1);
    MM(1, 1)
    __builtin_amdgcn_s_setprio(0);
    __builtin_amdgcn_s_barrier();

    // ---- phase 3: quadrant (1,0); drain next-tile loads once per K-tile
    LOADB(0)
    PHASE_SYNC
    __builtin_amdgcn_s_setprio(1);
    MM(1, 0)
    __builtin_amdgcn_s_setprio(0);
    if (pf) asm volatile("s_waitcnt vmcnt(0)" ::: "memory");
    __builtin_amdgcn_s_barrier();
  }

  // epilogue
  const long cb = bz * strC;
#pragma unroll
  for (int m = 0; m < 8; ++m) {
    const int r0 = wr * 128 + m * 16 + (lane >> 4) * 4;
#pragma unroll
    for (int n = 0; n < 4; ++n) {
      const int c = bcol + wc * 64 + n * 16 + lr;
      const float bv = bias ? bias[c] : 0.0f;
#pragma unroll
      for (int r = 0; r < 4; ++r) {
        const int row = brow + r0 + r;
        const long orow = REMAP ? (long)((row >> 11) * CS + PAST_N + (row & (SEQ - 1)))
                                : (long)row;
        const float val = (acc[m][n][r] + bv) * scale;
        if (EPI == 0 || EPI == 2) Cf[cb + orow * (long)ldc + c] = val;
        if (EPI == 1 || EPI == 2) Cb[cb + orow * (long)ldc + c] = f2bf(val);
      }
    }
  }
}

// fp32 -> bf16 cast, 4 elems/thread
__global__ __launch_bounds__(256) void cast_bf16_kn(const float* __restrict__ in,
                                                    u16* __restrict__ out) {
  const int i = blockIdx.x * 256 + threadIdx.x;
  const float4 v = ((const float4*)in)[i];
  ushort4 o;
  o.x = f2bf(v.x); o.y = f2bf(v.y); o.z = f2bf(v.z); o.w = f2bf(v.w);
  ((ushort4*)out)[i] = o;
}

// past_k/past_v -> cache rows [b, 0..PAST). K path also emits bf16 into kb.
__global__ __launch_bounds__(256) void copy_past_kv(const float* __restrict__ pk,
                                                    const float* __restrict__ pv,
                                                    float* __restrict__ kc,
                                                    float* __restrict__ vc,
                                                    u16* __restrict__ kb) {
  const int i = blockIdx.x * 256 + threadIdx.x;  // < NB*PAST_N*DM/4
  const int d4 = DM / 4;
  const int row = i / d4;
  const int col = i - row * d4;
  const int bb = row >> 11, p = row & (PAST_N - 1);
  const long o = ((long)(bb * CS + p)) * d4 + col;
  if (blockIdx.z == 0) {
    const float4 v = ((const float4*)pk)[i];
    ((float4*)kc)[o] = v;
    ushort4 u;
    u.x = f2bf(v.x); u.y = f2bf(v.y); u.z = f2bf(v.z); u.w = f2bf(v.w);
    ((ushort4*)kb)[o] = u;
  } else {
    ((float4*)vc)[o] = ((const float4*)pv)[i];
  }
}

// v_cache [b][k][d] fp32 -> vT [b][d][k] bf16
__global__ __launch_bounds__(256) void transpose_cast(const float* __restrict__ vcache,
                                                      u16* __restrict__ vt) {
  __shared__ float tile[32][33];
  const int bb = blockIdx.z;
  const int k0 = blockIdx.x * 32, d0 = blockIdx.y * 32;
  const int tx = threadIdx.x & 31, ty = threadIdx.x >> 5;
  const float* src = vcache + (long)bb * CS * DM;
#pragma unroll
  for (int j = 0; j < 4; ++j)
    tile[ty + 8 * j][tx] = src[(long)(k0 + ty + 8 * j) * DM + d0 + tx];
  __syncthreads();
  u16* dst = vt + (long)bb * DM * CS;
#pragma unroll
  for (int j = 0; j < 4; ++j)
    dst[(long)(d0 + ty + 8 * j) * CS + k0 + tx] = f2bf(tile[tx][ty + 8 * j]);
}

// in-place row softmax over bf16 scores, row length CS=4096, one block/row
__global__ __launch_bounds__(256) void softmax_rows(u16* __restrict__ s) {
  const long row = blockIdx.x;
  u16* p = s + row * CS;
  const int t = threadIdx.x;
  const int lane = t & 63, w = t >> 6;
  float v[16];
  s16x8 c0 = ((const s16x8*)p)[t * 2];
  s16x8 c1 = ((const s16x8*)p)[t * 2 + 1];
#pragma unroll
  for (int i = 0; i < 8; ++i) {
    v[i] = bf2f((u16)c0[i]);
    v[8 + i] = bf2f((u16)c1[i]);
  }
  float m = v[0];
#pragma unroll
  for (int i = 1; i < 16; ++i) m = fmaxf(m, v[i]);
#pragma unroll
  for (int o = 32; o >= 1; o >>= 1) m = fmaxf(m, __shfl_xor(m, o, 64));
  __shared__ float red[4];
  if (lane == 0) red[w] = m;
  __syncthreads();
  m = fmaxf(fmaxf(red[0], red[1]), fmaxf(red[2], red[3]));
  float sum = 0.f;
#pragma unroll
  for (int i = 0; i < 16; ++i) {
    v[i] = __expf(v[i] - m);
    sum += v[i];
  }
#pragma unroll
  for (int o = 32; o >= 1; o >>= 1) sum += __shfl_xor(sum, o, 64);
  __syncthreads();
  if (lane == 0) red[w] = sum;
  __syncthreads();
  sum = red[0] + red[1] + red[2] + red[3];
  const float inv = 1.0f / sum;
#pragma unroll
  for (int i = 0; i < 8; ++i) {
    c0[i] = (short)f2bf(v[i] * inv);
    c1[i] = (short)f2bf(v[8 + i] * inv);
  }
  ((s16x8*)p)[t * 2] = c0;
  ((s16x8*)p)[t * 2 + 1] = c1;
}

extern "C" void kernel_launch(void* const* d_in, const int* in_sizes, int n_in,
                              void* d_out, int out_size, void* d_ws, size_t ws_size,
                              hipStream_t stream) {
  const float* x  = (const float*)d_in[0];
  const float* pk = (const float*)d_in[1];
  const float* pv = (const float*)d_in[2];
  const float* Wq = (const float*)d_in[3];
  const float* bq = (const float*)d_in[4];
  const float* Wk = (const float*)d_in[5];
  const float* bk = (const float*)d_in[6];
  const float* Wv = (const float*)d_in[7];
  const float* bv = (const float*)d_in[8];
  const float* Wo = (const float*)d_in[9];
  const float* bo = (const float*)d_in[10];

  float* out = (float*)d_out;
  float* kc = out + (long)NB * SEQ * DM;   // k_cache [4][4096][2048] fp32
  float* vc = kc + (long)NB * CS * DM;     // v_cache

  u16* ws = (u16*)d_ws;
  u16* xb  = ws;              // x bf16 [8192][2048]; reused as attn bf16 later
  u16* wqb = ws + 16777216;
  u16* wkb = wqb + 4194304;
  u16* wvb = wkb + 4194304;
  u16* wob = wvb + 4194304;
  u16* qb  = ws + 33554432;   // q bf16 (scaled) [8192][2048]
  u16* kb  = ws + 50331648;   // k_cache bf16 [4][4096][2048]
  u16* vtb = ws + 83886080;   // v_cache^T bf16 [4][2048][4096]
  u16* sc  = ws + 117440512;  // scores/weights bf16 [4][2048][4096]

  const float qscale = 0.022097086912079608f;  // 1/sqrt(2048)

  cast_bf16_kn<<<16384, 256, 0, stream>>>(x, xb);
  cast_bf16_kn<<<4096, 256, 0, stream>>>(Wq, wqb);
  cast_bf16_kn<<<4096, 256, 0, stream>>>(Wk, wkb);
  cast_bf16_kn<<<4096, 256, 0, stream>>>(Wv, wvb);
  cast_bf16_kn<<<4096, 256, 0, stream>>>(Wo, wob);

  // Q = (x Wq^T + bq) * qscale -> bf16
  gemm256<1, false><<<dim3(8, 32, 1), 512, 0, stream>>>(
      xb, wqb, nullptr, qb, bq, 2048, 2048, 2048, 2048, 0, 0, 0, qscale);
  // K -> fp32 cache + bf16 kb (fused cast)
  gemm256<2, true><<<dim3(8, 32, 1), 512, 0, stream>>>(
      xb, wkb, kc, kb, bk, 2048, 2048, 2048, 2048, 0, 0, 0, 1.0f);
  // V -> fp32 cache
  gemm256<0, true><<<dim3(8, 32, 1), 512, 0, stream>>>(
      xb, wvb, vc, nullptr, bv, 2048, 2048, 2048, 2048, 0, 0, 0, 1.0f);

  copy_past_kv<<<dim3(16384, 1, 2), 256, 0, stream>>>(pk, pv, kc, vc, kb);

  transpose_cast<<<dim3(128, 64, 4), 256, 0, stream>>>(vc, vtb);

  // scores = q_scaled . k_cache^T -> bf16 [4][2048][4096]
  gemm256<1, false><<<dim3(16, 8, 4), 512, 0, stream>>>(
      qb, kb, nullptr, sc, nullptr, 2048, 2048, 2048, 4096,
      2048L * 2048, 4096L * 2048, 2048L * 4096, 1.0f);

  softmax_rows<<<8192, 256, 0, stream>>>(sc);

  // attn = weights . v_cache  (B = vT, K-contiguous) -> bf16 into xb
  gemm256<1, false><<<dim3(8, 8, 4), 512, 0, stream>>>(
      sc, vtb, nullptr, xb, nullptr, 4096, 4096, 4096, 2048,
      2048L * 4096, 2048L * 4096, 2048L * 2048, 1.0f);

  // out = attn Wo^T + bo -> fp32
  gemm256<0, false><<<dim3(8, 32, 1), 512, 0, stream>>>(
      xb, wob, out, nullptr, bo, 2048, 2048, 2048, 2048, 0, 0, 0, 1.0f);
}